// Round 4
// baseline (463.786 us; speedup 1.0000x reference)
//
#include <hip/hip_runtime.h>
#include <math.h>

#define NB    16
#define NPTS  2048
#define LP2   516      // LDS transpose pitch for 512-row chunk (float4-aligned)
#define EPSB  1e-5f

struct K1Args {
    const float *x;
    const float *fc1_w, *fc1_b, *bn1_g, *bn1_b;
    const float *fc2_w, *fc2_b, *bn2_g, *bn2_b;
    const float *fc3_w, *fc3_b;
    const float *uw0, *ub0, *ps0, *ph0, *wr0;
    const float *uw1, *ub1, *ps1, *ph1, *wr1;
    const float *uw2, *ub2, *ps2, *ph2, *wr2;
    const float *uw3, *ub3, *ps3, *ph3, *wr3;
    const float *fc4_w, *fc4_b;
    float *H;          // [NPTS][NB][6] h4 values for the head kernel
};

// ---------------------------------------------------------------------------
// K1: one block per batch (16 blocks x 1024 threads). Thread owns rows
// r0=2*tid, r1=2*tid+1 in registers through encoder + 4 relmods.
// BN1/BN2 stats: redundant in-thread over all 16 batches via quadratic forms.
// M = X^T U per relmod: chunked LDS transpose + 6x6 register-tile dots +
// wave butterfly + LDS combine. Only __syncthreads - no grid sync.
// ---------------------------------------------------------------------------
__global__ __launch_bounds__(1024) void relnet_main(K1Args a)
{
    __shared__ float w1[18], b1[6], w2[72], b2[12], w3[144], b3[12];
    __shared__ float Wu[4][144], Bu[4][12], w4[72], b4[6];
    __shared__ float A1[9], v1[3], wb1[3], gb1[2];   // bn1 quad-form helpers
    __shared__ float A2[36], v2[6], wb2[6], gb2[2];  // bn2 quad-form helpers
    __shared__ float scc[4];
    __shared__ float xT[12 * LP2], uT[12 * LP2];     // 49.5 KB
    __shared__ float Part[16][4][36];                // 9.2 KB
    __shared__ float Ml[144];

    const int tid   = threadIdx.x;
    const int batch = blockIdx.x;
    const int r0    = tid * 2, r1 = r0 + 1;

    // ---- weights -> LDS
    if (tid < 144) {
        w3[tid] = a.fc3_w[tid];
        Wu[0][tid] = a.uw0[tid]; Wu[1][tid] = a.uw1[tid];
        Wu[2][tid] = a.uw2[tid]; Wu[3][tid] = a.uw3[tid];
    }
    if (tid < 18) w1[tid] = a.fc1_w[tid];
    if (tid < 6)  { b1[tid] = a.fc1_b[tid]; b4[tid] = a.fc4_b[tid]; }
    if (tid < 72) { w2[tid] = a.fc2_w[tid]; w4[tid] = a.fc4_w[tid]; }
    if (tid < 12) {
        b2[tid] = a.fc2_b[tid]; b3[tid] = a.fc3_b[tid];
        Bu[0][tid] = a.ub0[tid]; Bu[1][tid] = a.ub1[tid];
        Bu[2][tid] = a.ub2[tid]; Bu[3][tid] = a.ub3[tid];
    }
    __syncthreads();

    // ---- derived quad-form constants (exact algebra):
    //   sum_c h_c   = wbar.x + beta      (h = W x + b)
    //   sum_c h_c^2 = x^T (sum_c w w^T) x + (2 sum_c b_c w_c).x + sum b^2
    if (tid < 9) {
        int i = tid / 3, j = tid % 3; float s = 0.f;
        for (int c = 0; c < 6; ++c) s += w1[c*3+i] * w1[c*3+j];
        A1[tid] = s;
    } else if (tid >= 16 && tid < 52) {
        int k = tid - 16, i = k / 6, j = k % 6; float s = 0.f;
        for (int c = 0; c < 12; ++c) s += w2[c*6+i] * w2[c*6+j];
        A2[k] = s;
    } else if (tid >= 64 && tid < 67) {
        int i = tid - 64; float s = 0.f;
        for (int c = 0; c < 6; ++c) s += b1[c] * w1[c*3+i];
        v1[i] = 2.f * s;
    } else if (tid >= 68 && tid < 74) {
        int i = tid - 68; float s = 0.f;
        for (int c = 0; c < 12; ++c) s += b2[c] * w2[c*6+i];
        v2[i] = 2.f * s;
    } else if (tid >= 80 && tid < 83) {
        int i = tid - 80; float s = 0.f;
        for (int c = 0; c < 6; ++c) s += w1[c*3+i];
        wb1[i] = s;
    } else if (tid >= 84 && tid < 90) {
        int i = tid - 84; float s = 0.f;
        for (int c = 0; c < 12; ++c) s += w2[c*6+i];
        wb2[i] = s;
    } else if (tid == 96) {
        float g = 0.f, bt = 0.f;
        for (int c = 0; c < 6; ++c) { g = fmaf(b1[c], b1[c], g); bt += b1[c]; }
        gb1[0] = g; gb1[1] = bt;
    } else if (tid == 97) {
        float g = 0.f, bt = 0.f;
        for (int c = 0; c < 12; ++c) { g = fmaf(b2[c], b2[c], g); bt += b2[c]; }
        gb2[0] = g; gb2[1] = bt;
    } else if (tid >= 100 && tid < 104) {
        int r = tid - 100; float p, h, w;
        if      (r == 0) { p = a.ps0[0]; h = a.ph0[0]; w = a.wr0[0]; }
        else if (r == 1) { p = a.ps1[0]; h = a.ph1[0]; w = a.wr1[0]; }
        else if (r == 2) { p = a.ps2[0]; h = a.ph2[0]; w = a.wr2[0]; }
        else             { p = a.ps3[0]; h = a.ph3[0]; w = a.wr3[0]; }
        scc[r] = p * h * w * (1.f / (float)NPTS);
    }
    __syncthreads();

    // =====================================================================
    // Encoder. pass1: bn1 stats via quad form (no h1 materialization).
    // =====================================================================
    float s1A = 16.f * gb1[1], q1A = 16.f * gb1[0];
    float s1B = s1A, q1B = q1A;
    for (int bb = 0; bb < NB; ++bb) {
        const float2* xp = (const float2*)(a.x + (size_t)(bb * NPTS + r0) * 3);
        float2 f0 = xp[0], f1 = xp[1], f2 = xp[2];
        float xA0 = f0.x, xA1 = f0.y, xA2 = f1.x;
        float xB0 = f1.y, xB1 = f2.x, xB2 = f2.y;
        s1A += fmaf(wb1[0], xA0, fmaf(wb1[1], xA1, wb1[2] * xA2));
        s1B += fmaf(wb1[0], xB0, fmaf(wb1[1], xB1, wb1[2] * xB2));
        float t0 = fmaf(A1[0], xA0, fmaf(A1[1], xA1, fmaf(A1[2], xA2, v1[0])));
        float t1 = fmaf(A1[3], xA0, fmaf(A1[4], xA1, fmaf(A1[5], xA2, v1[1])));
        float t2 = fmaf(A1[6], xA0, fmaf(A1[7], xA1, fmaf(A1[8], xA2, v1[2])));
        q1A += fmaf(xA0, t0, fmaf(xA1, t1, xA2 * t2));
        t0 = fmaf(A1[0], xB0, fmaf(A1[1], xB1, fmaf(A1[2], xB2, v1[0])));
        t1 = fmaf(A1[3], xB0, fmaf(A1[4], xB1, fmaf(A1[5], xB2, v1[1])));
        t2 = fmaf(A1[6], xB0, fmaf(A1[7], xB1, fmaf(A1[8], xB2, v1[2])));
        q1B += fmaf(xB0, t0, fmaf(xB1, t1, xB2 * t2));
    }
    const float m1A = s1A * (1.f/96.f);
    const float i1A = 1.f / sqrtf(q1A*(1.f/96.f) - m1A*m1A + EPSB);
    const float m1B = s1B * (1.f/96.f);
    const float i1B = 1.f / sqrtf(q1B*(1.f/96.f) - m1B*m1B + EPSB);
    const float G1A = a.bn1_g[r0] * i1A, E1A = a.bn1_b[r0];
    const float G1B = a.bn1_g[r1] * i1B, E1B = a.bn1_b[r1];

    // pass2: bn2 stats via quad form over a1; capture own-batch a1
    float s2A = 16.f * gb2[1], q2A = 16.f * gb2[0];
    float s2B = s2A, q2B = q2A;
    float a1oA[6], a1oB[6];
    for (int bb = 0; bb < NB; ++bb) {
        const float2* xp = (const float2*)(a.x + (size_t)(bb * NPTS + r0) * 3);
        float2 f0 = xp[0], f1 = xp[1], f2 = xp[2];
        float xA0 = f0.x, xA1 = f0.y, xA2 = f1.x;
        float xB0 = f1.y, xB1 = f2.x, xB2 = f2.y;
        float a1A[6], a1B[6];
#pragma unroll
        for (int c = 0; c < 6; ++c) {
            float hA = fmaf(w1[c*3], xA0, fmaf(w1[c*3+1], xA1, fmaf(w1[c*3+2], xA2, b1[c])));
            float hB = fmaf(w1[c*3], xB0, fmaf(w1[c*3+1], xB1, fmaf(w1[c*3+2], xB2, b1[c])));
            a1A[c] = fmaxf(fmaf(hA - m1A, G1A, E1A), 0.f);
            a1B[c] = fmaxf(fmaf(hB - m1B, G1B, E1B), 0.f);
        }
        float sA = 0.f, sB = 0.f, qA = 0.f, qB = 0.f;
#pragma unroll
        for (int i = 0; i < 6; ++i) {
            sA = fmaf(wb2[i], a1A[i], sA);
            sB = fmaf(wb2[i], a1B[i], sB);
            float tA = v2[i], tB = v2[i];
#pragma unroll
            for (int j = 0; j < 6; ++j) {
                tA = fmaf(A2[i*6+j], a1A[j], tA);
                tB = fmaf(A2[i*6+j], a1B[j], tB);
            }
            qA = fmaf(a1A[i], tA, qA);
            qB = fmaf(a1B[i], tB, qB);
        }
        s2A += sA; q2A += qA; s2B += sB; q2B += qB;
        if (bb == batch) {
#pragma unroll
            for (int i = 0; i < 6; ++i) { a1oA[i] = a1A[i]; a1oB[i] = a1B[i]; }
        }
    }
    const float m2A = s2A * (1.f/192.f);
    const float i2A = 1.f / sqrtf(q2A*(1.f/192.f) - m2A*m2A + EPSB);
    const float m2B = s2B * (1.f/192.f);
    const float i2B = 1.f / sqrtf(q2B*(1.f/192.f) - m2B*m2B + EPSB);
    const float G2A = a.bn2_g[r0] * i2A, E2A = a.bn2_b[r0];
    const float G2B = a.bn2_g[r1] * i2B, E2B = a.bn2_b[r1];

    float rowA[12], rowB[12];
    {
        float a2t[12];
#pragma unroll
        for (int c = 0; c < 12; ++c) {
            float h = b2[c];
#pragma unroll
            for (int d = 0; d < 6; ++d) h = fmaf(w2[c*6+d], a1oA[d], h);
            a2t[c] = fmaxf(fmaf(h - m2A, G2A, E2A), 0.f);
        }
#pragma unroll
        for (int c = 0; c < 12; ++c) {
            float h = b3[c];
#pragma unroll
            for (int d = 0; d < 12; ++d) h = fmaf(w3[c*12+d], a2t[d], h);
            rowA[c] = 1.f / (1.f + expf(-h));
        }
#pragma unroll
        for (int c = 0; c < 12; ++c) {
            float h = b2[c];
#pragma unroll
            for (int d = 0; d < 6; ++d) h = fmaf(w2[c*6+d], a1oB[d], h);
            a2t[c] = fmaxf(fmaf(h - m2B, G2B, E2B), 0.f);
        }
#pragma unroll
        for (int c = 0; c < 12; ++c) {
            float h = b3[c];
#pragma unroll
            for (int d = 0; d < 12; ++d) h = fmaf(w3[c*12+d], a2t[d], h);
            rowB[c] = 1.f / (1.f + expf(-h));
        }
    }

    // =====================================================================
    // 4 relmods, block-local M reduction.
    // =====================================================================
    const int tile = tid & 3;
    const int xh   = (tile >> 1) * 6;       // x half (rows of M)
    const int uh   = (tile & 1) * 6;        // u half (cols of M)
    const int seg  = (tid >> 2) & 127;      // float4 row-segment within chunk
    const int grp  = tid >> 9;              // handles chunks with c&1 == grp
    const int wvid = tid >> 6;

#pragma unroll 1
    for (int r = 0; r < 4; ++r) {
        float acc[36];
#pragma unroll
        for (int i = 0; i < 36; ++i) acc[i] = 0.f;

#pragma unroll 1
        for (int c = 0; c < 4; ++c) {
            __syncthreads();
            if ((tid >> 8) == c) {          // this thread's rows are in chunk c
                const int lr = r0 - 512 * c;
#pragma unroll
                for (int k = 0; k < 12; ++k) {
                    float uAk = Bu[r][k], uBk = Bu[r][k];
#pragma unroll
                    for (int d = 0; d < 12; ++d) {
                        uAk = fmaf(Wu[r][k*12+d], rowA[d], uAk);
                        uBk = fmaf(Wu[r][k*12+d], rowB[d], uBk);
                    }
                    xT[k*LP2 + lr]     = rowA[k];
                    xT[k*LP2 + lr + 1] = rowB[k];
                    uT[k*LP2 + lr]     = fmaxf(uAk, 0.f);
                    uT[k*LP2 + lr + 1] = fmaxf(uBk, 0.f);
                }
            }
            __syncthreads();
            if ((c & 1) == grp) {
                float4 uv[6];
#pragma unroll
                for (int ee = 0; ee < 6; ++ee)
                    uv[ee] = ((const float4*)(uT + (uh + ee) * LP2))[seg];
#pragma unroll
                for (int dd = 0; dd < 6; ++dd) {
                    float4 xv = ((const float4*)(xT + (xh + dd) * LP2))[seg];
#pragma unroll
                    for (int ee = 0; ee < 6; ++ee) {
                        float m = acc[dd*6+ee];
                        m = fmaf(xv.x, uv[ee].x, m);
                        m = fmaf(xv.y, uv[ee].y, m);
                        m = fmaf(xv.z, uv[ee].z, m);
                        m = fmaf(xv.w, uv[ee].w, m);
                        acc[dd*6+ee] = m;
                    }
                }
            }
        }
        // wave butterfly over seg bits (lanes 2..5), then cross-wave via LDS
#pragma unroll
        for (int i = 0; i < 36; ++i) {
            float v = acc[i];
            v += __shfl_xor(v, 4);
            v += __shfl_xor(v, 8);
            v += __shfl_xor(v, 16);
            v += __shfl_xor(v, 32);
            acc[i] = v;
        }
        if ((tid & 60) == 0) {
#pragma unroll
            for (int i = 0; i < 36; ++i) Part[wvid][tile][i] = acc[i];
        }
        __syncthreads();
        if (tid < 144) {
            const int d = tid / 12, e = tid - d * 12;
            const int qd = (d >= 6) ? 2 : 0, qe = (e >= 6) ? 1 : 0;
            const int rg = (d % 6) * 6 + (e % 6);
            float sm = 0.f;
#pragma unroll
            for (int w = 0; w < 16; ++w) sm += Part[w][qd + qe][rg];
            Ml[tid] = sm;
        }
        __syncthreads();

        // apply: f = coef*(x.M - |x|^2 u) + x   (recompute u; saves VGPRs)
        const float coef = scc[r];
        {
            float u[12];
#pragma unroll
            for (int k = 0; k < 12; ++k) {
                float t = Bu[r][k];
#pragma unroll
                for (int d = 0; d < 12; ++d) t = fmaf(Wu[r][k*12+d], rowA[d], t);
                u[k] = fmaxf(t, 0.f);
            }
            float xx = 0.f;
#pragma unroll
            for (int d = 0; d < 12; ++d) xx = fmaf(rowA[d], rowA[d], xx);
            float fo[12];
#pragma unroll
            for (int e = 0; e < 12; ++e) {
                float av = 0.f;
#pragma unroll
                for (int d = 0; d < 12; ++d) av = fmaf(rowA[d], Ml[d*12+e], av);
                fo[e] = fmaf(coef, fmaf(-xx, u[e], av), rowA[e]);
            }
#pragma unroll
            for (int d = 0; d < 12; ++d) rowA[d] = fo[d];
        }
        {
            float u[12];
#pragma unroll
            for (int k = 0; k < 12; ++k) {
                float t = Bu[r][k];
#pragma unroll
                for (int d = 0; d < 12; ++d) t = fmaf(Wu[r][k*12+d], rowB[d], t);
                u[k] = fmaxf(t, 0.f);
            }
            float xx = 0.f;
#pragma unroll
            for (int d = 0; d < 12; ++d) xx = fmaf(rowB[d], rowB[d], xx);
            float fo[12];
#pragma unroll
            for (int e = 0; e < 12; ++e) {
                float av = 0.f;
#pragma unroll
                for (int d = 0; d < 12; ++d) av = fmaf(rowB[d], Ml[d*12+e], av);
                fo[e] = fmaf(coef, fmaf(-xx, u[e], av), rowB[e]);
            }
#pragma unroll
            for (int d = 0; d < 12; ++d) rowB[d] = fo[d];
        }
    }

    // ---- fc4 -> h4 partial values for the head ([n][b][6] layout)
#pragma unroll
    for (int c = 0; c < 6; ++c) {
        float hA = b4[c], hB = b4[c];
#pragma unroll
        for (int d = 0; d < 12; ++d) {
            hA = fmaf(w4[c*12+d], rowA[d], hA);
            hB = fmaf(w4[c*12+d], rowB[d], hB);
        }
        a.H[((size_t)r0 * NB + batch) * 6 + c] = hA;
        a.H[((size_t)r1 * NB + batch) * 6 + c] = hB;
    }
}

// ---------------------------------------------------------------------------
// K2: head. thread=(b,n), b=tid&15; bn4 stats via 16-lane butterfly.
// ---------------------------------------------------------------------------
__global__ __launch_bounds__(128) void relnet_head(
    const float* __restrict__ H,
    const float* __restrict__ bn4_g, const float* __restrict__ bn4_b,
    const float* __restrict__ fc5_w, const float* __restrict__ fc5_b,
    const float* __restrict__ fc6_w, const float* __restrict__ fc6_b,
    const float* __restrict__ fc7_w, const float* __restrict__ fc7_b,
    float* __restrict__ out)
{
    __shared__ float w5[18], b5[3], w6[3], w7[6], hb[3];
    const int tid = threadIdx.x;
    if (tid < 18) w5[tid] = fc5_w[tid];
    if (tid < 3)  { b5[tid] = fc5_b[tid]; w6[tid] = fc6_w[tid]; }
    if (tid < 6)  w7[tid] = fc7_w[tid];
    if (tid == 0) { hb[0] = fc6_b[0]; hb[1] = fc7_b[0]; hb[2] = fc7_b[1]; }
    __syncthreads();

    const int b  = tid & 15;
    const int n  = blockIdx.x * 8 + (tid >> 4);
    const float2* hp = (const float2*)(H + ((size_t)n * NB + b) * 6);
    float2 f0 = hp[0], f1 = hp[1], f2 = hp[2];
    float h4[6] = { f0.x, f0.y, f1.x, f1.y, f2.x, f2.y };

    float s = 0.f, q = 0.f;
#pragma unroll
    for (int c = 0; c < 6; ++c) { s += h4[c]; q = fmaf(h4[c], h4[c], q); }
#pragma unroll
    for (int m = 1; m <= 8; m <<= 1) { s += __shfl_xor(s, m); q += __shfl_xor(q, m); }
    const float mm = s * (1.f/96.f);
    const float iv = 1.f / sqrtf(q*(1.f/96.f) - mm*mm + EPSB);
    const float g4 = bn4_g[n] * iv, e4 = bn4_b[n];

    float a4[6];
#pragma unroll
    for (int c = 0; c < 6; ++c) a4[c] = fmaxf(fmaf(h4[c] - mm, g4, e4), 0.f);

    float a5[3];
#pragma unroll
    for (int c = 0; c < 3; ++c) {
        float h = b5[c];
#pragma unroll
        for (int d = 0; d < 6; ++d) h = fmaf(w5[c*6+d], a4[d], h);
        a5[c] = fmaxf(h, 0.f);
    }
    const float cls = fmaf(w6[0], a5[0], fmaf(w6[1], a5[1], fmaf(w6[2], a5[2], hb[0])));
    const float g0  = fmaf(w7[0], a5[0], fmaf(w7[1], a5[1], fmaf(w7[2], a5[2], hb[1])));
    const float g1v = fmaf(w7[3], a5[0], fmaf(w7[4], a5[1], fmaf(w7[5], a5[2], hb[2])));
    float* op = out + ((size_t)b * NPTS + n) * 3;
    op[0] = cls; op[1] = g0; op[2] = g1v;
}

// ---------------------------------------------------------------------------
extern "C" void kernel_launch(void* const* d_in, const int* in_sizes, int n_in,
                              void* d_out, int out_size, void* d_ws, size_t ws_size,
                              hipStream_t stream)
{
    K1Args ka;
    ka.x     = (const float*)d_in[0];
    ka.fc1_w = (const float*)d_in[1];  ka.fc1_b = (const float*)d_in[2];
    ka.bn1_g = (const float*)d_in[3];  ka.bn1_b = (const float*)d_in[4];
    ka.fc2_w = (const float*)d_in[5];  ka.fc2_b = (const float*)d_in[6];
    ka.bn2_g = (const float*)d_in[7];  ka.bn2_b = (const float*)d_in[8];
    ka.fc3_w = (const float*)d_in[9];  ka.fc3_b = (const float*)d_in[10];
    ka.uw0 = (const float*)d_in[11]; ka.ub0 = (const float*)d_in[12];
    ka.ps0 = (const float*)d_in[13]; ka.ph0 = (const float*)d_in[14]; ka.wr0 = (const float*)d_in[15];
    ka.uw1 = (const float*)d_in[16]; ka.ub1 = (const float*)d_in[17];
    ka.ps1 = (const float*)d_in[18]; ka.ph1 = (const float*)d_in[19]; ka.wr1 = (const float*)d_in[20];
    ka.uw2 = (const float*)d_in[21]; ka.ub2 = (const float*)d_in[22];
    ka.ps2 = (const float*)d_in[23]; ka.ph2 = (const float*)d_in[24]; ka.wr2 = (const float*)d_in[25];
    ka.uw3 = (const float*)d_in[26]; ka.ub3 = (const float*)d_in[27];
    ka.ps3 = (const float*)d_in[28]; ka.ph3 = (const float*)d_in[29]; ka.wr3 = (const float*)d_in[30];
    ka.fc4_w = (const float*)d_in[31]; ka.fc4_b = (const float*)d_in[32];
    ka.H = (float*)d_ws;   // 2048*16*6 floats = 786 KB

    relnet_main<<<NB, 1024, 0, stream>>>(ka);

    relnet_head<<<NPTS / 8, 128, 0, stream>>>(
        (const float*)d_ws,
        (const float*)d_in[33], (const float*)d_in[34],
        (const float*)d_in[35], (const float*)d_in[36],
        (const float*)d_in[37], (const float*)d_in[38],
        (const float*)d_in[39], (const float*)d_in[40],
        (float*)d_out);
}

// Round 5
// 264.754 us; speedup vs baseline: 1.7518x; 1.7518x over previous
//
#include <hip/hip_runtime.h>
#include <math.h>

#define NB    16
#define NPTS  2048
#define NROW  (NB * NPTS)
#define CHUNK 128
#define NCH   16      // NPTS / CHUNK
#define LPAD  132     // CHUNK + 4, LDS transpose pitch
#define EPSB  1e-5f

struct KArgs {
    const float *x;
    const float *fc1_w, *fc1_b, *bn1_g, *bn1_b;
    const float *fc2_w, *fc2_b, *bn2_g, *bn2_b;
    const float *fc3_w, *fc3_b;
    const float *uw0, *ub0, *ps0, *ph0, *wr0;
    const float *uw1, *ub1, *ps1, *ph1, *wr1;
    const float *uw2, *ub2, *ps2, *ph2, *wr2;
    const float *uw3, *ub3, *ps3, *ph3, *wr3;
    const float *fc4_w, *fc4_b, *bn4_g, *bn4_b;
    const float *fc5_w, *fc5_b, *fc6_w, *fc6_b, *fc7_w, *fc7_b;
    int    *cnt;          // [5*16] group-barrier arrive counters (pre-zeroed)
    float2 *G;            // [NROW] bn4 stat partials, layout [b][n]
    float  *Pa, *Pb;      // [256*144] M partial ping-pong
    float  *out;
};

// ---------------------------------------------------------------------------
// 16-block group barrier: normal stores -> threadfence -> arrive -> spin.
// Device-scope atomics + agent acquire handle cross-XCD visibility (G16/m20).
// ---------------------------------------------------------------------------
__device__ __forceinline__ void group_barrier(int* c, int tid)
{
    __syncthreads();                      // all block threads' writes issued
    if (tid == 0) {
        __threadfence();                  // make partials visible device-wide
        atomicAdd(c, 1);
        while (__hip_atomic_load(c, __ATOMIC_ACQUIRE, __HIP_MEMORY_SCOPE_AGENT) < 16)
            __builtin_amdgcn_s_sleep(2);
        __threadfence();                  // acquire: invalidate stale caches
    }
    __syncthreads();
}

// 144 dot products of length CHUNK over the block's LDS-transposed rows.
__device__ __forceinline__ void block_dots(const float* xT, const float* uT,
                                           int tid, float* __restrict__ Pout, int blk)
{
    for (int k = tid; k < 144; k += CHUNK) {
        const int d = k / 12, e = k - d * 12;
        const float4* xp = (const float4*)(xT + d * LPAD);
        const float4* up = (const float4*)(uT + e * LPAD);
        float m = 0.f;
#pragma unroll
        for (int r = 0; r < CHUNK / 4; ++r) {
            float4 A = xp[r], C = up[r];
            m = fmaf(A.x, C.x, m); m = fmaf(A.y, C.y, m);
            m = fmaf(A.z, C.z, m); m = fmaf(A.w, C.w, m);
        }
        Pout[blk * 144 + k] = m;
    }
}

__global__ __launch_bounds__(128) void relnet_fused(KArgs a)
{
    __shared__ float w1[18], b1[6], w2[72], b2[12], w3[144], b3[12];
    __shared__ float Wu[4][144], Bu[4][12];
    __shared__ float w4[72], b4[6], w5[18], b5[3], w6[3], w7[6], hb[3];
    __shared__ float xT[12 * LPAD], uT[12 * LPAD], Ml[144];

    const int tid   = threadIdx.x;
    const int blk   = blockIdx.x;
    const int batch = blk >> 4, ch = blk & 15;
    const int n     = ch * CHUNK + tid;          // 0..2047
    const int gRow  = batch * NPTS + n;

    // ---- weights -> LDS (once)
    for (int k = tid; k < 144; k += 128) {
        w3[k] = a.fc3_w[k];
        Wu[0][k] = a.uw0[k]; Wu[1][k] = a.uw1[k];
        Wu[2][k] = a.uw2[k]; Wu[3][k] = a.uw3[k];
    }
    if (tid < 18) { w1[tid] = a.fc1_w[tid]; w5[tid] = a.fc5_w[tid]; }
    if (tid < 6)  { b1[tid] = a.fc1_b[tid]; b4[tid] = a.fc4_b[tid]; w7[tid] = a.fc7_w[tid]; }
    if (tid < 72) { w2[tid] = a.fc2_w[tid]; w4[tid] = a.fc4_w[tid]; }
    if (tid < 12) {
        b2[tid] = a.fc2_b[tid]; b3[tid] = a.fc3_b[tid];
        Bu[0][tid] = a.ub0[tid]; Bu[1][tid] = a.ub1[tid];
        Bu[2][tid] = a.ub2[tid]; Bu[3][tid] = a.ub3[tid];
    }
    if (tid < 3)  { b5[tid] = a.fc5_b[tid]; w6[tid] = a.fc6_w[tid]; }
    if (tid == 0) { hb[0] = a.fc6_b[0]; hb[1] = a.fc7_b[0]; hb[2] = a.fc7_b[1]; }
    __syncthreads();

    // =====================================================================
    // P0: encoder. bn1/bn2 stats computed REDUNDANTLY per thread over all
    // 16 batches of this n (no sync needed); own row -> registers.
    // =====================================================================
    float xs0[NB], xs1[NB], xs2[NB];
#pragma unroll
    for (int bb = 0; bb < NB; ++bb) {
        const float* xp = a.x + (bb * NPTS + n) * 3;
        xs0[bb] = xp[0]; xs1[bb] = xp[1]; xs2[bb] = xp[2];
    }
    // bn1 stats over (b,c): 96 vals
    float s = 0.f, q = 0.f;
#pragma unroll
    for (int bb = 0; bb < NB; ++bb)
#pragma unroll
        for (int c = 0; c < 6; ++c) {
            float h = fmaf(w1[c*3], xs0[bb], fmaf(w1[c*3+1], xs1[bb], fmaf(w1[c*3+2], xs2[bb], b1[c])));
            s += h; q = fmaf(h, h, q);
        }
    const float m1 = s * (1.f/96.f);
    const float i1 = 1.f / sqrtf(q*(1.f/96.f) - m1*m1 + EPSB);
    const float g1 = a.bn1_g[n] * i1, e1 = a.bn1_b[n];

    // bn2 stats over (b,c): 192 vals; capture own h2 on the fly
    float h2o[12];
    s = 0.f; q = 0.f;
#pragma unroll
    for (int bb = 0; bb < NB; ++bb) {
        float a1v[6];
#pragma unroll
        for (int c = 0; c < 6; ++c) {
            float h = fmaf(w1[c*3], xs0[bb], fmaf(w1[c*3+1], xs1[bb], fmaf(w1[c*3+2], xs2[bb], b1[c])));
            a1v[c] = fmaxf(fmaf(h - m1, g1, e1), 0.f);
        }
#pragma unroll
        for (int c = 0; c < 12; ++c) {
            float h = b2[c];
#pragma unroll
            for (int d = 0; d < 6; ++d) h = fmaf(w2[c*6+d], a1v[d], h);
            s += h; q = fmaf(h, h, q);
            if (bb == batch) h2o[c] = h;
        }
    }
    const float m2 = s * (1.f/192.f);
    const float i2 = 1.f / sqrtf(q*(1.f/192.f) - m2*m2 + EPSB);
    const float g2 = a.bn2_g[n] * i2, e2 = a.bn2_b[n];

    float a2[12];
#pragma unroll
    for (int c = 0; c < 12; ++c) a2[c] = fmaxf(fmaf(h2o[c] - m2, g2, e2), 0.f);

    float row[12];
#pragma unroll
    for (int c = 0; c < 12; ++c) {
        float h = b3[c];
#pragma unroll
        for (int d = 0; d < 12; ++d) h = fmaf(w3[c*12+d], a2[d], h);
        row[c] = 1.f / (1.f + expf(-h));
    }

    // M1 partials for this chunk
    {
        float u[12];
#pragma unroll
        for (int k = 0; k < 12; ++k) {
            float acc = Bu[0][k];
#pragma unroll
            for (int d = 0; d < 12; ++d) acc = fmaf(Wu[0][k*12+d], row[d], acc);
            u[k] = fmaxf(acc, 0.f);
        }
#pragma unroll
        for (int k = 0; k < 12; ++k) { xT[k*LPAD + tid] = row[k]; uT[k*LPAD + tid] = u[k]; }
        __syncthreads();
        block_dots(xT, uT, tid, a.Pa, blk);
    }
    group_barrier(a.cnt + 0*16 + batch, tid);     // M1 partials visible (batch group)

    // =====================================================================
    // relmod 1..3: apply from Pin, produce next-M partials into Pout
    // =====================================================================
#pragma unroll
    for (int r = 0; r < 3; ++r) {
        const float* Pin  = (r == 1) ? a.Pb : a.Pa;   // r=0:Pa, r=1:Pb, r=2:Pa
        float*       Pout = (r == 1) ? a.Pa : a.Pb;
        const float* psp = (r == 0) ? a.ps0 : (r == 1) ? a.ps1 : a.ps2;
        const float* php = (r == 0) ? a.ph0 : (r == 1) ? a.ph1 : a.ph2;
        const float* wrp = (r == 0) ? a.wr0 : (r == 1) ? a.wr1 : a.wr2;
        const float coef = wrp[0] * psp[0] * php[0] * (1.f / (float)NPTS);

        for (int k = tid; k < 144; k += 128) {
            float sm = 0.f;
#pragma unroll
            for (int c = 0; c < NCH; ++c) sm += Pin[(batch * NCH + c) * 144 + k];
            Ml[k] = sm;
        }
        __syncthreads();

        float u[12];
#pragma unroll
        for (int k = 0; k < 12; ++k) {
            float acc = Bu[r][k];
#pragma unroll
            for (int d = 0; d < 12; ++d) acc = fmaf(Wu[r][k*12+d], row[d], acc);
            u[k] = fmaxf(acc, 0.f);
        }
        float xx = 0.f;
#pragma unroll
        for (int d = 0; d < 12; ++d) xx = fmaf(row[d], row[d], xx);
        float fo[12];
#pragma unroll
        for (int e = 0; e < 12; ++e) {
            float acc = 0.f;
#pragma unroll
            for (int d = 0; d < 12; ++d) acc = fmaf(row[d], Ml[d*12+e], acc);
            fo[e] = fmaf(coef, fmaf(-xx, u[e], acc), row[e]);
        }
#pragma unroll
        for (int d = 0; d < 12; ++d) row[d] = fo[d];

        // next relmod's unary + partials
        float un[12];
#pragma unroll
        for (int k = 0; k < 12; ++k) {
            float acc = Bu[r+1][k];
#pragma unroll
            for (int d = 0; d < 12; ++d) acc = fmaf(Wu[r+1][k*12+d], row[d], acc);
            un[k] = fmaxf(acc, 0.f);
        }
        __syncthreads();   // all lanes done reading Ml/xT before overwrite
#pragma unroll
        for (int k = 0; k < 12; ++k) { xT[k*LPAD + tid] = row[k]; uT[k*LPAD + tid] = un[k]; }
        __syncthreads();
        block_dots(xT, uT, tid, Pout, blk);
        group_barrier(a.cnt + (r + 1)*16 + batch, tid);   // batch group
    }

    // =====================================================================
    // relmod 4 apply (Pin = Pb) + fc4 -> bn4 stat partials
    // =====================================================================
    float h4[6];
    {
        for (int k = tid; k < 144; k += 128) {
            float sm = 0.f;
#pragma unroll
            for (int c = 0; c < NCH; ++c) sm += a.Pb[(batch * NCH + c) * 144 + k];
            Ml[k] = sm;
        }
        __syncthreads();
        const float coef = a.wr3[0] * a.ps3[0] * a.ph3[0] * (1.f / (float)NPTS);
        float u[12];
#pragma unroll
        for (int k = 0; k < 12; ++k) {
            float acc = Bu[3][k];
#pragma unroll
            for (int d = 0; d < 12; ++d) acc = fmaf(Wu[3][k*12+d], row[d], acc);
            u[k] = fmaxf(acc, 0.f);
        }
        float xx = 0.f;
#pragma unroll
        for (int d = 0; d < 12; ++d) xx = fmaf(row[d], row[d], xx);
        float fo[12];
#pragma unroll
        for (int e = 0; e < 12; ++e) {
            float acc = 0.f;
#pragma unroll
            for (int d = 0; d < 12; ++d) acc = fmaf(row[d], Ml[d*12+e], acc);
            fo[e] = fmaf(coef, fmaf(-xx, u[e], acc), row[e]);
        }
#pragma unroll
        for (int d = 0; d < 12; ++d) row[d] = fo[d];

        float ss = 0.f, qq = 0.f;
#pragma unroll
        for (int c = 0; c < 6; ++c) {
            float h = b4[c];
#pragma unroll
            for (int d = 0; d < 12; ++d) h = fmaf(w4[c*12+d], row[d], h);
            h4[c] = h; ss += h; qq = fmaf(h, h, qq);
        }
        a.G[gRow] = make_float2(ss, qq);
    }
    group_barrier(a.cnt + 4*16 + ch, tid);   // bn4 partials: CHUNK group (all batches)

    // =====================================================================
    // final: bn4 + fc5 + heads
    // =====================================================================
    s = 0.f; q = 0.f;
#pragma unroll
    for (int bb = 0; bb < NB; ++bb) { float2 t = a.G[bb * NPTS + n]; s += t.x; q += t.y; }
    const float m4 = s * (1.f/96.f);
    const float i4 = 1.f / sqrtf(q*(1.f/96.f) - m4*m4 + EPSB);
    const float g4 = a.bn4_g[n] * i4, e4 = a.bn4_b[n];
    float a4[6];
#pragma unroll
    for (int c = 0; c < 6; ++c) a4[c] = fmaxf(fmaf(h4[c] - m4, g4, e4), 0.f);

    float a5[3];
#pragma unroll
    for (int c = 0; c < 3; ++c) {
        float h = b5[c];
#pragma unroll
        for (int d = 0; d < 6; ++d) h = fmaf(w5[c*6+d], a4[d], h);
        a5[c] = fmaxf(h, 0.f);
    }
    const float cls = fmaf(w6[0], a5[0], fmaf(w6[1], a5[1], fmaf(w6[2], a5[2], hb[0])));
    const float g0  = fmaf(w7[0], a5[0], fmaf(w7[1], a5[1], fmaf(w7[2], a5[2], hb[1])));
    const float g1v = fmaf(w7[3], a5[0], fmaf(w7[4], a5[1], fmaf(w7[5], a5[2], hb[2])));
    float* op = a.out + gRow * 3;
    op[0] = cls; op[1] = g0; op[2] = g1v;
}

// ---------------------------------------------------------------------------
extern "C" void kernel_launch(void* const* d_in, const int* in_sizes, int n_in,
                              void* d_out, int out_size, void* d_ws, size_t ws_size,
                              hipStream_t stream)
{
    KArgs ka;
    ka.x     = (const float*)d_in[0];
    ka.fc1_w = (const float*)d_in[1];  ka.fc1_b = (const float*)d_in[2];
    ka.bn1_g = (const float*)d_in[3];  ka.bn1_b = (const float*)d_in[4];
    ka.fc2_w = (const float*)d_in[5];  ka.fc2_b = (const float*)d_in[6];
    ka.bn2_g = (const float*)d_in[7];  ka.bn2_b = (const float*)d_in[8];
    ka.fc3_w = (const float*)d_in[9];  ka.fc3_b = (const float*)d_in[10];
    ka.uw0 = (const float*)d_in[11]; ka.ub0 = (const float*)d_in[12];
    ka.ps0 = (const float*)d_in[13]; ka.ph0 = (const float*)d_in[14]; ka.wr0 = (const float*)d_in[15];
    ka.uw1 = (const float*)d_in[16]; ka.ub1 = (const float*)d_in[17];
    ka.ps1 = (const float*)d_in[18]; ka.ph1 = (const float*)d_in[19]; ka.wr1 = (const float*)d_in[20];
    ka.uw2 = (const float*)d_in[21]; ka.ub2 = (const float*)d_in[22];
    ka.ps2 = (const float*)d_in[23]; ka.ph2 = (const float*)d_in[24]; ka.wr2 = (const float*)d_in[25];
    ka.uw3 = (const float*)d_in[26]; ka.ub3 = (const float*)d_in[27];
    ka.ps3 = (const float*)d_in[28]; ka.ph3 = (const float*)d_in[29]; ka.wr3 = (const float*)d_in[30];
    ka.fc4_w = (const float*)d_in[31]; ka.fc4_b = (const float*)d_in[32];
    ka.bn4_g = (const float*)d_in[33]; ka.bn4_b = (const float*)d_in[34];
    ka.fc5_w = (const float*)d_in[35]; ka.fc5_b = (const float*)d_in[36];
    ka.fc6_w = (const float*)d_in[37]; ka.fc6_b = (const float*)d_in[38];
    ka.fc7_w = (const float*)d_in[39]; ka.fc7_b = (const float*)d_in[40];

    float* ws = (float*)d_ws;
    ka.cnt = (int*)ws;                       // 80 ints (barrier counters)
    ka.Pa  = ws + 128;                       // 256*144 = 36864 floats
    ka.Pb  = ws + 128 + 36864;
    ka.G   = (float2*)(ws + 128 + 2 * 36864);// 32768 float2
    ka.out = (float*)d_out;

    // zero the arrive counters (harness poisons ws with 0xAA)
    hipMemsetAsync(ka.cnt, 0, 5 * 16 * sizeof(int), stream);

    relnet_fused<<<dim3(NB * NCH), dim3(CHUNK), 0, stream>>>(ka);
}